// Round 2
// baseline (253.507 us; speedup 1.0000x reference)
//
#include <hip/hip_runtime.h>
#include <hip/hip_bf16.h>
#include <stdint.h>

// Problem constants: B=64, L=96, C=32, H=256, NL=2, K=3, TAU=2, VTH=1
// n = b*32 + c indexes the B*C=2048 "rows"; layer width H=256.

using floatx4 = __attribute__((ext_vector_type(4))) float;
using intx4   = __attribute__((ext_vector_type(4))) int;

// ---------------------------------------------------------------------------
// prep: per output-neuron o (256 blocks x 64 threads)  [unchanged]
// ---------------------------------------------------------------------------
__global__ void prep_kernel(const float* __restrict__ w_enc,
                            const float* __restrict__ b_enc,
                            const float* __restrict__ w_rnn,
                            const float* __restrict__ b_rnn,
                            double* __restrict__ Wd,
                            double* __restrict__ C0d,
                            signed char* __restrict__ Bw8)
{
    const int o = blockIdx.x;
    const int lane = threadIdx.x;   // 64 threads
    const float4 w0v = *(const float4*)(w_rnn + (size_t)o * 256 + lane * 4);
    double a0 = 0.0, a1 = 0.0, a2 = 0.0, ab = 0.0;
#pragma unroll
    for (int e = 0; e < 4; ++e) {
        const int i = lane * 4 + e;
        const double wv = (double)(((const float*)&w0v)[e]);
        a0 += wv * (double)w_enc[i * 3 + 0];
        a1 += wv * (double)w_enc[i * 3 + 1];
        a2 += wv * (double)w_enc[i * 3 + 2];
        ab += wv * (double)b_enc[i];
    }
    for (int off = 32; off > 0; off >>= 1) {
        a0 += __shfl_down(a0, off, 64);
        a1 += __shfl_down(a1, off, 64);
        a2 += __shfl_down(a2, off, 64);
        ab += __shfl_down(ab, off, 64);
    }
    if (lane == 0) {
        Wd[o * 3 + 0] = a0;
        Wd[o * 3 + 1] = a1;
        Wd[o * 3 + 2] = a2;
        C0d[o] = ab + (double)b_rnn[o];
    }
    // i8 digit planes of w1 (layer-1), 4 consecutive k per lane
    const float4 w1v = *(const float4*)(w_rnn + 65536 + (size_t)o * 256 + lane * 4);
    unsigned int pack[4] = {0u, 0u, 0u, 0u};   // pack[l]: digits for e=0..3
#pragma unroll
    for (int e = 0; e < 4; ++e) {
        float f = ((const float*)&w1v)[e];
        int q = __double2int_rn((double)f * 134217728.0);   // w * 2^27, |q| <= 2^27
        int d3 = ((q + 64) & 127) - 64;  q = (q - d3) >> 7;
        int d2 = ((q + 64) & 127) - 64;  q = (q - d2) >> 7;
        int d1 = ((q + 64) & 127) - 64;  q = (q - d1) >> 7;
        int d0 = q;                       // |d0| <= 64
        pack[0] |= ((unsigned int)(d0 & 0xFF)) << (8 * e);
        pack[1] |= ((unsigned int)(d1 & 0xFF)) << (8 * e);
        pack[2] |= ((unsigned int)(d2 & 0xFF)) << (8 * e);
        pack[3] |= ((unsigned int)(d3 & 0xFF)) << (8 * e);
    }
#pragma unroll
    for (int l = 0; l < 4; ++l)
        *(unsigned int*)(Bw8 + ((size_t)o * 4 + l) * 256 + lane * 4) = pack[l];
}

// ---------------------------------------------------------------------------
// enc: layer-0 full scan.  [unchanged]
// ---------------------------------------------------------------------------
__global__ void enc_kernel(const float* __restrict__ inputs,
                           const double* __restrict__ Wd,
                           const double* __restrict__ C0d,
                           unsigned char* __restrict__ s0b)
{
    const int n = blockIdx.x;
    const int tidx = threadIdx.x;
    const int b = n >> 5, c = n & 31;
    __shared__ float xr[98];
    if (tidx < 96)       xr[tidx + 1] = inputs[((size_t)b * 96 + tidx) * 32 + c];
    else if (tidx == 96) xr[0]  = 0.0f;
    else if (tidx == 97) xr[97] = 0.0f;
    __syncthreads();
    const double W0 = Wd[tidx * 3], W1 = Wd[tidx * 3 + 1], W2 = Wd[tidx * 3 + 2];
    const double c0 = C0d[tidx];
    const int wid = tidx >> 6, lane = tidx & 63;
    float v = 0.0f;
    for (int t = 0; t < 96; ++t) {
        float cur = (float)((double)xr[t] * W0 + (double)xr[t + 1] * W1 +
                            (double)xr[t + 2] * W2 + c0);
        float vv = v + (cur - v) * 0.5f;
        int sp = (vv - 1.0f) >= 0.0f;
        v = sp ? 0.0f : vv;
        unsigned long long bal = __ballot(sp);
        if ((lane & 15) == 0) {
            const int j = lane >> 4;
            *(unsigned short*)(s0b + ((size_t)t * 2048 + n) * 32 + 8 * j + 2 * wid)
                = (unsigned short)(bal >> (16 * j));
        }
    }
}

// ---------------------------------------------------------------------------
// rnn R17: CROSS-GROUP software pipeline. 2-step groups, ping-pong acc sets
// A/B (statically named). Per iteration: issue group g+1's 32 MFMAs, then run
// group g's membrane+stores WHILE those MFMAs are in flight, alternating
// roles. This removes the per-group MFMA-pipe idle during membrane/store
// epilogues (why R15's deeper same-structure groups were zero-gain: the
// MFMA-phase/epilogue ratio was depth-invariant).
// Decision math BIT-IDENTICAL per step: i8 limb MFMA (exact), fp32 limb
// combine fmaf((float)a01, 2^-13, (float)a23*2^-27) == RN(exact sum);
// membrane in exact reference fp32 op order; vv*(1-s) hard reset. v-chain
// program order preserved (steps strictly sequential).
// C/D 16x16: M=(lane>>4)*4+reg -> out-col; N=lane&15 -> spike-row.
// ---------------------------------------------------------------------------
__global__ __launch_bounds__(128, 2) void rnn_kernel(
    const unsigned char* __restrict__ s0b,
    const signed char* __restrict__ Bw8,
    const float* __restrict__ b_rnn,
    float* __restrict__ out0,
    float* __restrict__ out1)
{
    const int tid  = threadIdx.x;
    const int wid  = tid >> 6, lane = tid & 63;
    const int m    = lane & 15, g = lane >> 4;
    const int job  = blockIdx.x * 2 + wid;          // 2048 jobs
    const int rt   = job >> 4;                      // 128 row-tiles
    const int nw   = rt * 16;
    const int o0   = (job & 15) * 16;               // 16 col-tiles

    // --- weight A-fragments (loop-invariant): 4 limbs x 4 chunks = 64 VGPRs
    intx4 bfrag[4][4];
#pragma unroll
    for (int l = 0; l < 4; ++l)
#pragma unroll
        for (int c = 0; c < 4; ++c)
            bfrag[l][c] = *(const intx4*)(Bw8 + ((size_t)(o0 + m) * 4 + l) * 256
                                               + c * 64 + g * 16);
    // per-lane bias for out-cols o0+4g .. o0+4g+3
    const float4 biasv = *(const float4*)(b_rnn + 256 + o0 + g * 4);

    // --- store base: spike-row nw+m, col o0+4g (16B-aligned) ---
    float* pb = out0 + ((size_t)(nw >> 5) * 96) * 8192
                     + (size_t)((nw & 31) + m) * 256 + o0 + g * 4;

    // --- mask stream: lane reads uint2 at row*32 + 8g ---
    const unsigned char* mp = s0b + ((size_t)(nw + m)) * 32 + 8 * g;

    floatx4 v = {0.f, 0.f, 0.f, 0.f};

    #define STEP_MFMA(MASK, ACC0, ACC1, ACC2, ACC3)                            \
    do {                                                                       \
        unsigned int hw_[4] = { (MASK).x & 0xFFFFu, (MASK).x >> 16,            \
                                (MASK).y & 0xFFFFu, (MASK).y >> 16 };          \
        _Pragma("unroll")                                                      \
        for (int c = 0; c < 4; ++c) {                                          \
            unsigned int h_ = hw_[c];                                          \
            intx4 a_;                                                          \
            a_.x = (int)(__umul24( h_        & 0xFu, 0x00204081u) & 0x01010101u); \
            a_.y = (int)(__umul24((h_ >> 4)  & 0xFu, 0x00204081u) & 0x01010101u); \
            a_.z = (int)(__umul24((h_ >> 8)  & 0xFu, 0x00204081u) & 0x01010101u); \
            a_.w = (int)(__umul24((h_ >> 12) & 0xFu, 0x00204081u) & 0x01010101u); \
            ACC0 = __builtin_amdgcn_mfma_i32_16x16x64_i8(bfrag[0][c], a_, ACC0, 0, 0, 0); \
            ACC1 = __builtin_amdgcn_mfma_i32_16x16x64_i8(bfrag[1][c], a_, ACC1, 0, 0, 0); \
            ACC2 = __builtin_amdgcn_mfma_i32_16x16x64_i8(bfrag[2][c], a_, ACC2, 0, 0, 0); \
            ACC3 = __builtin_amdgcn_mfma_i32_16x16x64_i8(bfrag[3][c], a_, ACC3, 0, 0, 0); \
        }                                                                      \
    } while (0)

    #define MEMBRANE(ACC0, ACC1, ACC2, ACC3, SV)                               \
    do {                                                                       \
        _Pragma("unroll")                                                      \
        for (int r = 0; r < 4; ++r) {                                          \
            int a01 = (ACC0)[r] * 128 + (ACC1)[r];   /* exact, |.| < 2^22 */   \
            int a23 = (ACC2)[r] * 128 + (ACC3)[r];                             \
            float cur = fmaf((float)a01, 0x1p-13f, (float)a23 * 0x1p-27f)      \
                        + ((const float*)&biasv)[r];                           \
            float vv = v[r];                                                   \
            vv = vv + (cur - vv) * 0.5f;                                       \
            float s = ((vv - 1.0f) >= 0.0f) ? 1.0f : 0.0f;                     \
            v[r] = vv * (1.0f - s);                                            \
            (SV)[r] = s;                                                       \
        }                                                                      \
    } while (0)

    // ---- pipeline state: group-A accumulators (persist across iterations) --
    intx4 A00 = {0,0,0,0}, A01 = {0,0,0,0}, A02 = {0,0,0,0}, A03 = {0,0,0,0};
    intx4 A10 = {0,0,0,0}, A11 = {0,0,0,0}, A12 = {0,0,0,0}, A13 = {0,0,0,0};

    // prologue: masks for steps 0..3, issue group 0 (steps 0,1) MFMAs
    uint2 mA0 = *(const uint2*)(mp);
    uint2 mA1 = *(const uint2*)(mp + 65536);
    uint2 mB0 = *(const uint2*)(mp + 2 * 65536);
    uint2 mB1 = *(const uint2*)(mp + 3 * 65536);
    STEP_MFMA(mA0, A00, A01, A02, A03);
    STEP_MFMA(mA1, A10, A11, A12, A13);

    // main loop: t = 0,4,...,88 (23 iterations, 4 steps each)
    for (int t = 0; t < 92; t += 4) {
        // prefetch masks for steps t+4, t+5 (next A group)
        uint2 mC0 = *(const uint2*)(mp + (size_t)(t + 4) * 65536);
        uint2 mC1 = *(const uint2*)(mp + (size_t)(t + 5) * 65536);

        // issue group B (steps t+2, t+3) MFMAs — overlap with A's membrane
        intx4 B00 = {0,0,0,0}, B01 = {0,0,0,0}, B02 = {0,0,0,0}, B03 = {0,0,0,0};
        intx4 B10 = {0,0,0,0}, B11 = {0,0,0,0}, B12 = {0,0,0,0}, B13 = {0,0,0,0};
        STEP_MFMA(mB0, B00, B01, B02, B03);
        STEP_MFMA(mB1, B10, B11, B12, B13);

        // membrane + store group A (steps t, t+1) while B MFMAs in flight
        floatx4 svA0, svA1;
        MEMBRANE(A00, A01, A02, A03, svA0);
        *(floatx4*)pb = svA0;
        MEMBRANE(A10, A11, A12, A13, svA1);
        *(floatx4*)(pb + 8192) = svA1;

        // prefetch masks for steps t+6, t+7 (next B group)
        uint2 mD0 = *(const uint2*)(mp + (size_t)(t + 6) * 65536);
        uint2 mD1 = *(const uint2*)(mp + (size_t)(t + 7) * 65536);

        // issue next group A (steps t+4, t+5) MFMAs — overlap with B's membrane
        A00 = (intx4){0,0,0,0}; A01 = (intx4){0,0,0,0};
        A02 = (intx4){0,0,0,0}; A03 = (intx4){0,0,0,0};
        A10 = (intx4){0,0,0,0}; A11 = (intx4){0,0,0,0};
        A12 = (intx4){0,0,0,0}; A13 = (intx4){0,0,0,0};
        STEP_MFMA(mC0, A00, A01, A02, A03);
        STEP_MFMA(mC1, A10, A11, A12, A13);

        // membrane + store group B (steps t+2, t+3)
        floatx4 svB0, svB1;
        MEMBRANE(B00, B01, B02, B03, svB0);
        *(floatx4*)(pb + 16384) = svB0;
        MEMBRANE(B10, B11, B12, B13, svB1);
        *(floatx4*)(pb + 24576) = svB1;

        pb += 32768;
        mB0 = mD0; mB1 = mD1;
    }

    // epilogue: A holds steps 92,93 (in flight); mB holds masks for 94,95
    {
        intx4 B00 = {0,0,0,0}, B01 = {0,0,0,0}, B02 = {0,0,0,0}, B03 = {0,0,0,0};
        intx4 B10 = {0,0,0,0}, B11 = {0,0,0,0}, B12 = {0,0,0,0}, B13 = {0,0,0,0};
        STEP_MFMA(mB0, B00, B01, B02, B03);
        STEP_MFMA(mB1, B10, B11, B12, B13);

        floatx4 svA0, svA1, svB0, svB1;
        MEMBRANE(A00, A01, A02, A03, svA0);
        *(floatx4*)pb = svA0;
        MEMBRANE(A10, A11, A12, A13, svA1);
        *(floatx4*)(pb + 8192) = svA1;
        MEMBRANE(B00, B01, B02, B03, svB0);
        *(floatx4*)(pb + 16384) = svB0;
        MEMBRANE(B10, B11, B12, B13, svB1);
        *(floatx4*)(pb + 24576) = svB1;
        *(floatx4*)(out1 + (size_t)(nw + m) * 256 + o0 + g * 4) = svB1;
    }
    #undef STEP_MFMA
    #undef MEMBRANE
}

// ---------------------------------------------------------------------------
extern "C" void kernel_launch(void* const* d_in, const int* in_sizes, int n_in,
                              void* d_out, int out_size, void* d_ws, size_t ws_size,
                              hipStream_t stream) {
    const float* inputs = (const float*)d_in[0];   // [64,96,32]
    const float* w_enc  = (const float*)d_in[1];   // [256,1,3]
    const float* b_enc  = (const float*)d_in[2];   // [256]
    const float* w_rnn  = (const float*)d_in[3];   // [2,256,256]
    const float* b_rnn  = (const float*)d_in[4];   // [2,256]

    float* out0 = (float*)d_out;                       // [64,96,8192]
    float* out1 = out0 + (size_t)64 * 96 * 8192;       // [64,8192]

    char* ws = (char*)d_ws;
    double*      Wd  = (double*)(ws);                  //  768 doubles  [0,6144)
    double*      C0d = (double*)(ws + 6144);           //  256 doubles  [6144,8192)
    signed char* Bw8 = (signed char*)(ws + 8192);      //  256*4*256 i8 [8192,270336)
    unsigned char* s0b = (unsigned char*)(ws + 270336);// 98*65536 B spike bits (2 pad slots)

    prep_kernel<<<256, 64, 0, stream>>>(w_enc, b_enc, w_rnn, b_rnn, Wd, C0d, Bw8);
    enc_kernel<<<2048, 256, 0, stream>>>(inputs, Wd, C0d, s0b);
    rnn_kernel<<<1024, 128, 0, stream>>>(s0b, Bw8, b_rnn, out0, out1);
}

// Round 3
// 252.452 us; speedup vs baseline: 1.0042x; 1.0042x over previous
//
#include <hip/hip_runtime.h>
#include <hip/hip_bf16.h>
#include <stdint.h>

// Problem constants: B=64, L=96, C=32, H=256, NL=2, K=3, TAU=2, VTH=1
// n = b*32 + c indexes the B*C=2048 "rows"; layer width H=256.

using floatx4 = __attribute__((ext_vector_type(4))) float;
using intx4   = __attribute__((ext_vector_type(4))) int;

// ---------------------------------------------------------------------------
// prep: per output-neuron o (256 blocks x 64 threads)  [unchanged]
// ---------------------------------------------------------------------------
__global__ void prep_kernel(const float* __restrict__ w_enc,
                            const float* __restrict__ b_enc,
                            const float* __restrict__ w_rnn,
                            const float* __restrict__ b_rnn,
                            double* __restrict__ Wd,
                            double* __restrict__ C0d,
                            signed char* __restrict__ Bw8)
{
    const int o = blockIdx.x;
    const int lane = threadIdx.x;   // 64 threads
    const float4 w0v = *(const float4*)(w_rnn + (size_t)o * 256 + lane * 4);
    double a0 = 0.0, a1 = 0.0, a2 = 0.0, ab = 0.0;
#pragma unroll
    for (int e = 0; e < 4; ++e) {
        const int i = lane * 4 + e;
        const double wv = (double)(((const float*)&w0v)[e]);
        a0 += wv * (double)w_enc[i * 3 + 0];
        a1 += wv * (double)w_enc[i * 3 + 1];
        a2 += wv * (double)w_enc[i * 3 + 2];
        ab += wv * (double)b_enc[i];
    }
    for (int off = 32; off > 0; off >>= 1) {
        a0 += __shfl_down(a0, off, 64);
        a1 += __shfl_down(a1, off, 64);
        a2 += __shfl_down(a2, off, 64);
        ab += __shfl_down(ab, off, 64);
    }
    if (lane == 0) {
        Wd[o * 3 + 0] = a0;
        Wd[o * 3 + 1] = a1;
        Wd[o * 3 + 2] = a2;
        C0d[o] = ab + (double)b_rnn[o];
    }
    // i8 digit planes of w1 (layer-1), 4 consecutive k per lane
    const float4 w1v = *(const float4*)(w_rnn + 65536 + (size_t)o * 256 + lane * 4);
    unsigned int pack[4] = {0u, 0u, 0u, 0u};   // pack[l]: digits for e=0..3
#pragma unroll
    for (int e = 0; e < 4; ++e) {
        float f = ((const float*)&w1v)[e];
        int q = __double2int_rn((double)f * 134217728.0);   // w * 2^27, |q| <= 2^27
        int d3 = ((q + 64) & 127) - 64;  q = (q - d3) >> 7;
        int d2 = ((q + 64) & 127) - 64;  q = (q - d2) >> 7;
        int d1 = ((q + 64) & 127) - 64;  q = (q - d1) >> 7;
        int d0 = q;                       // |d0| <= 64
        pack[0] |= ((unsigned int)(d0 & 0xFF)) << (8 * e);
        pack[1] |= ((unsigned int)(d1 & 0xFF)) << (8 * e);
        pack[2] |= ((unsigned int)(d2 & 0xFF)) << (8 * e);
        pack[3] |= ((unsigned int)(d3 & 0xFF)) << (8 * e);
    }
#pragma unroll
    for (int l = 0; l < 4; ++l)
        *(unsigned int*)(Bw8 + ((size_t)o * 4 + l) * 256 + lane * 4) = pack[l];
}

// ---------------------------------------------------------------------------
// enc: layer-0 full scan.  [unchanged]
// ---------------------------------------------------------------------------
__global__ void enc_kernel(const float* __restrict__ inputs,
                           const double* __restrict__ Wd,
                           const double* __restrict__ C0d,
                           unsigned char* __restrict__ s0b)
{
    const int n = blockIdx.x;
    const int tidx = threadIdx.x;
    const int b = n >> 5, c = n & 31;
    __shared__ float xr[98];
    if (tidx < 96)       xr[tidx + 1] = inputs[((size_t)b * 96 + tidx) * 32 + c];
    else if (tidx == 96) xr[0]  = 0.0f;
    else if (tidx == 97) xr[97] = 0.0f;
    __syncthreads();
    const double W0 = Wd[tidx * 3], W1 = Wd[tidx * 3 + 1], W2 = Wd[tidx * 3 + 2];
    const double c0 = C0d[tidx];
    const int wid = tidx >> 6, lane = tidx & 63;
    float v = 0.0f;
    for (int t = 0; t < 96; ++t) {
        float cur = (float)((double)xr[t] * W0 + (double)xr[t + 1] * W1 +
                            (double)xr[t + 2] * W2 + c0);
        float vv = v + (cur - v) * 0.5f;
        int sp = (vv - 1.0f) >= 0.0f;
        v = sp ? 0.0f : vv;
        unsigned long long bal = __ballot(sp);
        if ((lane & 15) == 0) {
            const int j = lane >> 4;
            *(unsigned short*)(s0b + ((size_t)t * 2048 + n) * 32 + 8 * j + 2 * wid)
                = (unsigned short)(bal >> (16 * j));
        }
    }
}

// ---------------------------------------------------------------------------
// rnn R18: (a) chunk-level CROSS-STEP MFMA interleave — per chunk c, issue
// 4 MFMAs of step X then 4 of step Y: 8 independent accumulate chains, same-
// accumulator spacing ~8 MFMAs (~163 cyc) instead of ~3 (~61 cyc), so any
// plausible i8 MFMA accumulate latency is covered even at 2 waves/SIMD.
// (b) XCD-aware block->(rt,ct) swizzle: all 16 col-jobs of a row-tile share
// one XCD (blockIdx%8 = XCD round-robin): mask loads hit the same L2 (6 MB
// fetched once per XCD region instead of ~8x), store lines stay XCD-local.
// Block's two waves remain ADJACENT col-tiles (one full 128-B line per row).
// Decision math BIT-IDENTICAL per step (integer MFMA accumulation is
// order-free; membrane in exact reference fp32 op order; vv*(1-s) reset).
// C/D 16x16: M=(lane>>4)*4+reg -> out-col; N=lane&15 -> spike-row.
// ---------------------------------------------------------------------------
__global__ __launch_bounds__(128, 2) void rnn_kernel(
    const unsigned char* __restrict__ s0b,
    const signed char* __restrict__ Bw8,
    const float* __restrict__ b_rnn,
    float* __restrict__ out0,
    float* __restrict__ out1)
{
    const int tid  = threadIdx.x;
    const int wid  = tid >> 6, lane = tid & 63;
    const int m    = lane & 15, g = lane >> 4;

    // --- XCD-aware job mapping (bijective): 8 blocks of a row-tile share
    // blockIdx%8 (one XCD); block's 2 waves = adjacent col-tiles.
    const int bidx = blockIdx.x;            // 0..1023
    const int xcd  = bidx & 7;
    const int u    = bidx >> 3;             // 0..127
    const int rt   = 16 * xcd + (u & 15);   // 128 row-tiles
    const int cp   = u >> 4;                // 0..7 col-pairs
    const int ct   = cp * 2 + wid;          // 16 col-tiles
    const int nw   = rt * 16;
    const int o0   = ct * 16;

    // --- weight A-fragments (loop-invariant): 4 limbs x 4 chunks = 64 VGPRs
    intx4 bfrag[4][4];
#pragma unroll
    for (int l = 0; l < 4; ++l)
#pragma unroll
        for (int c = 0; c < 4; ++c)
            bfrag[l][c] = *(const intx4*)(Bw8 + ((size_t)(o0 + m) * 4 + l) * 256
                                               + c * 64 + g * 16);
    // per-lane bias for out-cols o0+4g .. o0+4g+3
    const float4 biasv = *(const float4*)(b_rnn + 256 + o0 + g * 4);

    // --- store base: spike-row nw+m, col o0+4g (16B-aligned) ---
    float* pb = out0 + ((size_t)(nw >> 5) * 96) * 8192
                     + (size_t)((nw & 31) + m) * 256 + o0 + g * 4;

    // --- mask stream: lane reads uint2 at row*32 + 8g ---
    const unsigned char* mp = s0b + ((size_t)(nw + m)) * 32 + 8 * g;

    floatx4 v = {0.f, 0.f, 0.f, 0.f};

    // Two steps' MFMAs interleaved at chunk level: 8 independent chains.
    #define PAIR_MFMA(MX, MY, XA0, XA1, XA2, XA3, YA0, YA1, YA2, YA3)          \
    do {                                                                       \
        unsigned int hwx_[4] = { (MX).x & 0xFFFFu, (MX).x >> 16,               \
                                 (MX).y & 0xFFFFu, (MX).y >> 16 };             \
        unsigned int hwy_[4] = { (MY).x & 0xFFFFu, (MY).x >> 16,               \
                                 (MY).y & 0xFFFFu, (MY).y >> 16 };             \
        _Pragma("unroll")                                                      \
        for (int c = 0; c < 4; ++c) {                                          \
            unsigned int hx_ = hwx_[c], hy_ = hwy_[c];                         \
            intx4 ax_, ay_;                                                    \
            ax_.x = (int)(__umul24( hx_        & 0xFu, 0x00204081u) & 0x01010101u); \
            ax_.y = (int)(__umul24((hx_ >> 4)  & 0xFu, 0x00204081u) & 0x01010101u); \
            ax_.z = (int)(__umul24((hx_ >> 8)  & 0xFu, 0x00204081u) & 0x01010101u); \
            ax_.w = (int)(__umul24((hx_ >> 12) & 0xFu, 0x00204081u) & 0x01010101u); \
            XA0 = __builtin_amdgcn_mfma_i32_16x16x64_i8(bfrag[0][c], ax_, XA0, 0, 0, 0); \
            XA1 = __builtin_amdgcn_mfma_i32_16x16x64_i8(bfrag[1][c], ax_, XA1, 0, 0, 0); \
            XA2 = __builtin_amdgcn_mfma_i32_16x16x64_i8(bfrag[2][c], ax_, XA2, 0, 0, 0); \
            XA3 = __builtin_amdgcn_mfma_i32_16x16x64_i8(bfrag[3][c], ax_, XA3, 0, 0, 0); \
            ay_.x = (int)(__umul24( hy_        & 0xFu, 0x00204081u) & 0x01010101u); \
            ay_.y = (int)(__umul24((hy_ >> 4)  & 0xFu, 0x00204081u) & 0x01010101u); \
            ay_.z = (int)(__umul24((hy_ >> 8)  & 0xFu, 0x00204081u) & 0x01010101u); \
            ay_.w = (int)(__umul24((hy_ >> 12) & 0xFu, 0x00204081u) & 0x01010101u); \
            YA0 = __builtin_amdgcn_mfma_i32_16x16x64_i8(bfrag[0][c], ay_, YA0, 0, 0, 0); \
            YA1 = __builtin_amdgcn_mfma_i32_16x16x64_i8(bfrag[1][c], ay_, YA1, 0, 0, 0); \
            YA2 = __builtin_amdgcn_mfma_i32_16x16x64_i8(bfrag[2][c], ay_, YA2, 0, 0, 0); \
            YA3 = __builtin_amdgcn_mfma_i32_16x16x64_i8(bfrag[3][c], ay_, YA3, 0, 0, 0); \
        }                                                                      \
    } while (0)

    #define MEMBRANE(ACC0, ACC1, ACC2, ACC3, SV)                               \
    do {                                                                       \
        _Pragma("unroll")                                                      \
        for (int r = 0; r < 4; ++r) {                                          \
            int a01 = (ACC0)[r] * 128 + (ACC1)[r];   /* exact, |.| < 2^22 */   \
            int a23 = (ACC2)[r] * 128 + (ACC3)[r];                             \
            float cur = fmaf((float)a01, 0x1p-13f, (float)a23 * 0x1p-27f)      \
                        + ((const float*)&biasv)[r];                           \
            float vv = v[r];                                                   \
            vv = vv + (cur - vv) * 0.5f;                                       \
            float s = ((vv - 1.0f) >= 0.0f) ? 1.0f : 0.0f;                     \
            v[r] = vv * (1.0f - s);                                            \
            (SV)[r] = s;                                                       \
        }                                                                      \
    } while (0)

    // ---- pipeline state: group-A accumulators (persist across iterations) --
    intx4 A00 = {0,0,0,0}, A01 = {0,0,0,0}, A02 = {0,0,0,0}, A03 = {0,0,0,0};
    intx4 A10 = {0,0,0,0}, A11 = {0,0,0,0}, A12 = {0,0,0,0}, A13 = {0,0,0,0};

    // prologue: masks for steps 0..3, issue group 0 (steps 0,1) MFMAs
    uint2 mA0 = *(const uint2*)(mp);
    uint2 mA1 = *(const uint2*)(mp + 65536);
    uint2 mB0 = *(const uint2*)(mp + 2 * 65536);
    uint2 mB1 = *(const uint2*)(mp + 3 * 65536);
    PAIR_MFMA(mA0, mA1, A00, A01, A02, A03, A10, A11, A12, A13);

    // main loop: t = 0,4,...,88 (23 iterations, 4 steps each)
    for (int t = 0; t < 92; t += 4) {
        // prefetch masks for steps t+4, t+5 (next A group)
        uint2 mC0 = *(const uint2*)(mp + (size_t)(t + 4) * 65536);
        uint2 mC1 = *(const uint2*)(mp + (size_t)(t + 5) * 65536);

        // issue group B (steps t+2, t+3) MFMAs — overlap with A's membrane
        intx4 B00 = {0,0,0,0}, B01 = {0,0,0,0}, B02 = {0,0,0,0}, B03 = {0,0,0,0};
        intx4 B10 = {0,0,0,0}, B11 = {0,0,0,0}, B12 = {0,0,0,0}, B13 = {0,0,0,0};
        PAIR_MFMA(mB0, mB1, B00, B01, B02, B03, B10, B11, B12, B13);

        // membrane + store group A (steps t, t+1) while B MFMAs in flight
        floatx4 svA0, svA1;
        MEMBRANE(A00, A01, A02, A03, svA0);
        *(floatx4*)pb = svA0;
        MEMBRANE(A10, A11, A12, A13, svA1);
        *(floatx4*)(pb + 8192) = svA1;

        // prefetch masks for steps t+6, t+7 (next B group)
        uint2 mD0 = *(const uint2*)(mp + (size_t)(t + 6) * 65536);
        uint2 mD1 = *(const uint2*)(mp + (size_t)(t + 7) * 65536);

        // issue next group A (steps t+4, t+5) MFMAs — overlap with B's membrane
        A00 = (intx4){0,0,0,0}; A01 = (intx4){0,0,0,0};
        A02 = (intx4){0,0,0,0}; A03 = (intx4){0,0,0,0};
        A10 = (intx4){0,0,0,0}; A11 = (intx4){0,0,0,0};
        A12 = (intx4){0,0,0,0}; A13 = (intx4){0,0,0,0};
        PAIR_MFMA(mC0, mC1, A00, A01, A02, A03, A10, A11, A12, A13);

        // membrane + store group B (steps t+2, t+3)
        floatx4 svB0, svB1;
        MEMBRANE(B00, B01, B02, B03, svB0);
        *(floatx4*)(pb + 16384) = svB0;
        MEMBRANE(B10, B11, B12, B13, svB1);
        *(floatx4*)(pb + 24576) = svB1;

        pb += 32768;
        mB0 = mD0; mB1 = mD1;
    }

    // epilogue: A holds steps 92,93 (in flight); mB holds masks for 94,95
    {
        intx4 B00 = {0,0,0,0}, B01 = {0,0,0,0}, B02 = {0,0,0,0}, B03 = {0,0,0,0};
        intx4 B10 = {0,0,0,0}, B11 = {0,0,0,0}, B12 = {0,0,0,0}, B13 = {0,0,0,0};
        PAIR_MFMA(mB0, mB1, B00, B01, B02, B03, B10, B11, B12, B13);

        floatx4 svA0, svA1, svB0, svB1;
        MEMBRANE(A00, A01, A02, A03, svA0);
        *(floatx4*)pb = svA0;
        MEMBRANE(A10, A11, A12, A13, svA1);
        *(floatx4*)(pb + 8192) = svA1;
        MEMBRANE(B00, B01, B02, B03, svB0);
        *(floatx4*)(pb + 16384) = svB0;
        MEMBRANE(B10, B11, B12, B13, svB1);
        *(floatx4*)(pb + 24576) = svB1;
        *(floatx4*)(out1 + (size_t)(nw + m) * 256 + o0 + g * 4) = svB1;
    }
    #undef PAIR_MFMA
    #undef MEMBRANE
}

// ---------------------------------------------------------------------------
extern "C" void kernel_launch(void* const* d_in, const int* in_sizes, int n_in,
                              void* d_out, int out_size, void* d_ws, size_t ws_size,
                              hipStream_t stream) {
    const float* inputs = (const float*)d_in[0];   // [64,96,32]
    const float* w_enc  = (const float*)d_in[1];   // [256,1,3]
    const float* b_enc  = (const float*)d_in[2];   // [256]
    const float* w_rnn  = (const float*)d_in[3];   // [2,256,256]
    const float* b_rnn  = (const float*)d_in[4];   // [2,256]

    float* out0 = (float*)d_out;                       // [64,96,8192]
    float* out1 = out0 + (size_t)64 * 96 * 8192;       // [64,8192]

    char* ws = (char*)d_ws;
    double*      Wd  = (double*)(ws);                  //  768 doubles  [0,6144)
    double*      C0d = (double*)(ws + 6144);           //  256 doubles  [6144,8192)
    signed char* Bw8 = (signed char*)(ws + 8192);      //  256*4*256 i8 [8192,270336)
    unsigned char* s0b = (unsigned char*)(ws + 270336);// 98*65536 B spike bits (2 pad slots)

    prep_kernel<<<256, 64, 0, stream>>>(w_enc, b_enc, w_rnn, b_rnn, Wd, C0d, Bw8);
    enc_kernel<<<2048, 256, 0, stream>>>(inputs, Wd, C0d, s0b);
    rnn_kernel<<<1024, 128, 0, stream>>>(s0b, Bw8, b_rnn, out0, out1);
}